// Round 1
// 2841.726 us; speedup vs baseline: 1.3092x; 1.3092x over previous
//
#include <hip/hip_runtime.h>
#include <hip/hip_bf16.h>

#define NN 50000
#define NE 500000

// order-preserving float->uint encoding for atomicMax-based segment_max
__device__ __forceinline__ unsigned enc_ord(float x){
  unsigned b = __float_as_uint(x);
  return (b & 0x80000000u) ? ~b : (b | 0x80000000u);
}
__device__ __forceinline__ float dec_ord(unsigned k){
  unsigned b = (k & 0x80000000u) ? (k ^ 0x80000000u) : ~k;
  return __uint_as_float(b);
}
#define ENC_NEG_INF 0x007fffffu  // enc_ord(-inf)

__global__ void k_embed(const int* __restrict__ nt, const float* __restrict__ table,
                        float* __restrict__ nf){
  int i = blockIdx.x * 256 + threadIdx.x;
  if (i >= NN * 128) return;
  nf[i] = table[nt[i >> 7] * 128 + (i & 127)];
}

__global__ void k_init(float* __restrict__ h_new, unsigned* __restrict__ m_enc,
                       float* __restrict__ s){
  int i = blockIdx.x * 256 + threadIdx.x;
  if (i < NN * 256) h_new[i] = 0.f;
  if (i < NN * 4){ m_enc[i] = ENC_NEG_INF; s[i] = 0.f; }
}

// C[M x Nc] = A[M x K] @ W[K x Nc] (+ bias). fp32, fp32 accum.
// Block tile 128x128, 256 threads, 8x8 register micro-tile, BK=32.
// A staged TRANSPOSED into LDS (As[k][m], stride 132 to dodge bank conflicts).
// grid: ((M+127)/128, Nc/128). K must be a multiple of 32 (here 64/128/256).
__global__ __launch_bounds__(256) void k_gemm(
    const float* __restrict__ A, const float* __restrict__ W,
    const float* __restrict__ bias, float* __restrict__ C,
    int M, int K, int Nc){
  __shared__ float As[32][132];   // [k][m], padded stride
  __shared__ float Ws[32][128];   // [k][n]
  int tid = threadIdx.x;
  int row0 = blockIdx.x * 128;
  int col0 = blockIdx.y * 128;
  int tr = (tid >> 4) & 15;       // 0..15 -> rows {tr*4+i, 64+tr*4+i}
  int tc = tid & 15;              // 0..15 -> cols {tc*4+j, 64+tc*4+j}

  float acc[8][8];
  #pragma unroll
  for (int i = 0; i < 8; ++i)
    #pragma unroll
    for (int j = 0; j < 8; ++j) acc[i][j] = 0.f;

  for (int k0 = 0; k0 < K; k0 += 32){
    // stage A: 128 rows x 32 k -> transposed. 1024 float4, 4/thread, coalesced.
    #pragma unroll
    for (int q = 0; q < 4; ++q){
      int idx = tid + q * 256;
      int r  = idx >> 3;          // 0..127
      int kk = (idx & 7) * 4;     // 0..28
      float4 v = make_float4(0.f, 0.f, 0.f, 0.f);
      int gr = row0 + r;
      if (gr < M) v = *reinterpret_cast<const float4*>(A + (size_t)gr * K + k0 + kk);
      As[kk+0][r] = v.x; As[kk+1][r] = v.y; As[kk+2][r] = v.z; As[kk+3][r] = v.w;
    }
    // stage W: 32 k x 128 cols. 1024 float4, 4/thread, coalesced.
    #pragma unroll
    for (int q = 0; q < 4; ++q){
      int idx = tid + q * 256;
      int kk = idx >> 5;          // 0..31
      int cc = (idx & 31) * 4;    // 0..124
      *reinterpret_cast<float4*>(&Ws[kk][cc]) =
          *reinterpret_cast<const float4*>(W + (size_t)(k0 + kk) * Nc + col0 + cc);
    }
    __syncthreads();
    #pragma unroll 8
    for (int kk = 0; kk < 32; ++kk){
      float4 a0 = *reinterpret_cast<const float4*>(&As[kk][tr * 4]);
      float4 a1 = *reinterpret_cast<const float4*>(&As[kk][64 + tr * 4]);
      float4 b0 = *reinterpret_cast<const float4*>(&Ws[kk][tc * 4]);
      float4 b1 = *reinterpret_cast<const float4*>(&Ws[kk][64 + tc * 4]);
      float av[8] = {a0.x, a0.y, a0.z, a0.w, a1.x, a1.y, a1.z, a1.w};
      float bv[8] = {b0.x, b0.y, b0.z, b0.w, b1.x, b1.y, b1.z, b1.w};
      #pragma unroll
      for (int i = 0; i < 8; ++i)
        #pragma unroll
        for (int j = 0; j < 8; ++j)
          acc[i][j] += av[i] * bv[j];
    }
    __syncthreads();
  }

  float4 bia0 = make_float4(0.f, 0.f, 0.f, 0.f), bia1 = bia0;
  if (bias){
    bia0 = *reinterpret_cast<const float4*>(bias + col0 + tc * 4);
    bia1 = *reinterpret_cast<const float4*>(bias + col0 + 64 + tc * 4);
  }
  #pragma unroll
  for (int i = 0; i < 8; ++i){
    int gr = row0 + (i >> 2) * 64 + tr * 4 + (i & 3);
    if (gr < M){
      float4 v0 = make_float4(acc[i][0] + bia0.x, acc[i][1] + bia0.y,
                              acc[i][2] + bia0.z, acc[i][3] + bia0.w);
      float4 v1 = make_float4(acc[i][4] + bia1.x, acc[i][5] + bia1.y,
                              acc[i][6] + bia1.z, acc[i][7] + bia1.w);
      *reinterpret_cast<float4*>(C + (size_t)gr * Nc + col0 + tc * 4) = v0;
      *reinterpret_cast<float4*>(C + (size_t)gr * Nc + col0 + 64 + tc * 4) = v1;
    }
  }
}

// Per edge (128 cols): F = lrelu(F + f_ni[src] + f_nj[dst] + bias); logits[e][h] = <F_h, attn_h>
__global__ __launch_bounds__(256) void k_edge_build(
    float* __restrict__ F, const float* __restrict__ f_ni, const float* __restrict__ f_nj,
    const float* __restrict__ bias, const float* __restrict__ attn,
    const int* __restrict__ src, const int* __restrict__ dst,
    float* __restrict__ logits){
  int tid = threadIdx.x;
  int e = blockIdx.x * 2 + (tid >> 7);
  if (e >= NE) return;
  int c = tid & 127;
  int sN = src[e], dN = dst[e];
  size_t ix = (size_t)e * 128 + c;
  float v = F[ix] + f_ni[sN*128 + c] + f_nj[dN*128 + c] + bias[c];
  v = (v >= 0.f) ? v : 0.01f * v;
  F[ix] = v;
  // attn is (4,32) flattened: head h = c>>5 uses attn[h*32 + (c&31)] == attn[c]
  float p = v * attn[c];
  p += __shfl_xor(p, 16, 64);
  p += __shfl_xor(p, 8, 64);
  p += __shfl_xor(p, 4, 64);
  p += __shfl_xor(p, 2, 64);
  p += __shfl_xor(p, 1, 64);
  if ((c & 31) == 0) logits[e * 4 + (c >> 5)] = p;
}

__global__ void k_segmax(const float* __restrict__ logits, const int* __restrict__ dst,
                         unsigned* __restrict__ m_enc){
  int i = blockIdx.x * 256 + threadIdx.x;
  if (i >= NE * 4) return;
  atomicMax(&m_enc[dst[i >> 2] * 4 + (i & 3)], enc_ord(logits[i]));
}

__global__ void k_expsum(float* __restrict__ logits, const int* __restrict__ dst,
                         const unsigned* __restrict__ m_enc, float* __restrict__ s){
  int i = blockIdx.x * 256 + threadIdx.x;
  if (i >= NE * 4) return;
  int q = dst[i >> 2] * 4 + (i & 3);
  float ee = expf(logits[i] - dec_ord(m_enc[q]));
  logits[i] = ee;
  atomicAdd(&s[q], ee);
}

// One block per edge: h_new[dst] += h_src[src] * alpha  (256 cols = 4 heads x 64)
__global__ __launch_bounds__(256) void k_agg(
    const float* __restrict__ eel, const float* __restrict__ s,
    const float* __restrict__ h_src, const int* __restrict__ src,
    const int* __restrict__ dst, float* __restrict__ h_new){
  int e = blockIdx.x;
  int c = threadIdx.x;
  int h = c >> 6;
  int sN = src[e], dN = dst[e];
  float alpha = eel[e * 4 + h] / s[dN * 4 + h];
  atomicAdd(&h_new[dN * 256 + c], h_src[sN * 256 + c] * alpha);
}

__global__ void k_node_elu(const float* __restrict__ h_new, float* __restrict__ out){
  int i = blockIdx.x * 256 + threadIdx.x;
  if (i >= NN * 256) return;
  float v = h_new[i];
  out[i] = v > 0.f ? v : expm1f(v);
}

__global__ void k_edge_elu(const float* __restrict__ F, float* __restrict__ out){
  size_t i = (size_t)blockIdx.x * 256 + threadIdx.x;
  if (i >= (size_t)NE * 128) return;
  float v = F[i];
  out[i] = v > 0.f ? v : expm1f(v);
}

static void run_layer(const float* nf, int in_n, const float* ef, int in_e,
                      const float* Wsrc, const float* bsrc, const float* Wni,
                      const float* Wnj, const float* Wfij, const float* attn,
                      const float* bias, const int* src, const int* dst,
                      float* f_ni, float* f_nj, float* h_src, float* F,
                      float* logits, unsigned* m_enc, float* s, float* h_new,
                      float* nf_out, float* ef_out, hipStream_t stream){
  dim3 gN((NN + 127) / 128, 1);
  dim3 gN2((NN + 127) / 128, 2);
  dim3 gE((NE + 127) / 128, 1);
  k_gemm<<<gN,  256, 0, stream>>>(nf, Wni, nullptr, f_ni, NN, in_n, 128);
  k_gemm<<<gN,  256, 0, stream>>>(nf, Wnj, nullptr, f_nj, NN, in_n, 128);
  k_gemm<<<gN2, 256, 0, stream>>>(nf, Wsrc, bsrc, h_src, NN, in_n, 256);
  k_gemm<<<gE,  256, 0, stream>>>(ef, Wfij, nullptr, F, NE, in_e, 128);
  k_init<<<(NN*256)/256, 256, 0, stream>>>(h_new, m_enc, s);
  k_edge_build<<<NE/2, 256, 0, stream>>>(F, f_ni, f_nj, bias, attn, src, dst, logits);
  k_segmax<<<(NE*4 + 255)/256, 256, 0, stream>>>(logits, dst, m_enc);
  k_expsum<<<(NE*4 + 255)/256, 256, 0, stream>>>(logits, dst, m_enc, s);
  k_agg<<<NE, 256, 0, stream>>>(logits, s, h_src, src, dst, h_new);
  k_node_elu<<<(NN*256)/256, 256, 0, stream>>>(h_new, nf_out);
  k_edge_elu<<<(NE*128)/256, 256, 0, stream>>>(F, ef_out);
}

extern "C" void kernel_launch(void* const* d_in, const int* in_sizes, int n_in,
                              void* d_out, int out_size, void* d_ws, size_t ws_size,
                              hipStream_t stream){
  const int*   node_types = (const int*)d_in[0];
  const int*   src        = (const int*)d_in[1];
  const int*   dst        = (const int*)d_in[2];
  const float* efeats     = (const float*)d_in[3];
  const float* table      = (const float*)d_in[4];
  const float* W_src0 = (const float*)d_in[5];
  const float* b_src0 = (const float*)d_in[6];
  const float* W_ni0  = (const float*)d_in[7];
  const float* W_nj0  = (const float*)d_in[8];
  const float* W_fij0 = (const float*)d_in[9];
  const float* attn0  = (const float*)d_in[10];
  const float* bias0  = (const float*)d_in[11];
  const float* W_src1 = (const float*)d_in[12];
  const float* b_src1 = (const float*)d_in[13];
  const float* W_ni1  = (const float*)d_in[14];
  const float* W_nj1  = (const float*)d_in[15];
  const float* W_fij1 = (const float*)d_in[16];
  const float* attn1  = (const float*)d_in[17];
  const float* bias1  = (const float*)d_in[18];

  char* w = (char*)d_ws;
  auto alloc = [&](size_t bytes){ void* p = (void*)w; w += (bytes + 255) & ~(size_t)255; return p; };
  float*    nf_buf = (float*)   alloc((size_t)NN * 256 * 4);
  float*    f_ni   = (float*)   alloc((size_t)NN * 128 * 4);
  float*    f_nj   = (float*)   alloc((size_t)NN * 128 * 4);
  float*    h_src  = (float*)   alloc((size_t)NN * 256 * 4);
  float*    h_new  = (float*)   alloc((size_t)NN * 256 * 4);
  unsigned* m_enc  = (unsigned*)alloc((size_t)NN * 4 * 4);
  float*    s      = (float*)   alloc((size_t)NN * 4 * 4);
  float*    logits = (float*)   alloc((size_t)NE * 4 * 4);
  float*    F      = (float*)   alloc((size_t)NE * 128 * 4);

  float* out_nf = (float*)d_out;              // (NN, 256)
  float* out_ef = out_nf + (size_t)NN * 256;  // (NE, 128) — also doubles as ef1 staging

  // nf0 = embed_table[node_types]  (NN x 128)
  k_embed<<<(NN*128)/256, 256, 0, stream>>>(node_types, table, nf_buf);

  // Layer 0: in_n=128, in_e=64 -> nf1 (NN x 256) in nf_buf, ef1 (NE x 128) in out_ef
  run_layer(nf_buf, 128, efeats, 64,
            W_src0, b_src0, W_ni0, W_nj0, W_fij0, attn0, bias0,
            src, dst, f_ni, f_nj, h_src, F, logits, m_enc, s, h_new,
            nf_buf, out_ef, stream);

  // Layer 1: in_n=256, in_e=128 -> outputs straight to d_out
  run_layer(nf_buf, 256, out_ef, 128,
            W_src1, b_src1, W_ni1, W_nj1, W_fij1, attn1, bias1,
            src, dst, f_ni, f_nj, h_src, F, logits, m_enc, s, h_new,
            out_nf, out_ef, stream);
}

// Round 2
// 2096.507 us; speedup vs baseline: 1.7746x; 1.3555x over previous
//
#include <hip/hip_runtime.h>
#include <hip/hip_bf16.h>

#define NN 50000
#define NE 500000

__global__ void k_embed(const int* __restrict__ nt, const float* __restrict__ table,
                        float* __restrict__ nf){
  int i = blockIdx.x * 256 + threadIdx.x;
  if (i >= NN * 128) return;
  nf[i] = table[nt[i >> 7] * 128 + (i & 127)];
}

// ---------------- CSR build (once per launch; reused by both layers) ----------------
__global__ void k_zero2(int* __restrict__ cnt, int* __restrict__ cur){
  int i = blockIdx.x * 256 + threadIdx.x;
  if (i < NN){ cnt[i] = 0; cur[i] = 0; }
}

__global__ void k_hist(const int* __restrict__ dst, int* __restrict__ cnt){
  int e = blockIdx.x * 256 + threadIdx.x;
  if (e < NE) atomicAdd(&cnt[dst[e]], 1);
}

// single-block exclusive scan over NN counts -> off[0..NN]
__global__ __launch_bounds__(1024) void k_scan(const int* __restrict__ cnt,
                                               int* __restrict__ off){
  __shared__ int ws[16];
  __shared__ int blocktot;
  __shared__ int carry_s;
  int tid = threadIdx.x;
  int lane = tid & 63, wv = tid >> 6;
  if (tid == 0) carry_s = 0;
  for (int base = 0; base < NN; base += 1024){
    int i = base + tid;
    int v = (i < NN) ? cnt[i] : 0;
    int x = v;
    #pragma unroll
    for (int d = 1; d < 64; d <<= 1){
      int t = __shfl_up(x, d, 64);
      if (lane >= d) x += t;
    }
    if (lane == 63) ws[wv] = x;
    __syncthreads();                    // also orders carry_s init
    if (tid == 0){
      int a = 0;
      #pragma unroll
      for (int k2 = 0; k2 < 16; ++k2){ int t = ws[k2]; ws[k2] = a; a += t; }
      blocktot = a;
    }
    __syncthreads();
    int carry = carry_s;
    if (i < NN) off[i] = carry + ws[wv] + (x - v);   // exclusive
    __syncthreads();
    if (tid == 0) carry_s = carry + blocktot;
    __syncthreads();
  }
  if (tid == 0) off[NN] = carry_s;
}

__global__ void k_scatter(const int* __restrict__ src, const int* __restrict__ dst,
                          const int* __restrict__ off, int* __restrict__ cur,
                          int* __restrict__ perm_e, int* __restrict__ perm_s){
  int e = blockIdx.x * 256 + threadIdx.x;
  if (e >= NE) return;
  int d = dst[e];
  int pos = off[d] + atomicAdd(&cur[d], 1);
  perm_e[pos] = e;
  perm_s[pos] = src[e];
}

// ---------------- GEMM: C[M x Nc] = A[M x K] @ W[K x Nc] (+ bias) ----------------
// Block tile 128x128, 256 threads, 8x8 register micro-tile, BK=32.
__global__ __launch_bounds__(256) void k_gemm(
    const float* __restrict__ A, const float* __restrict__ W,
    const float* __restrict__ bias, float* __restrict__ C,
    int M, int K, int Nc){
  __shared__ float As[32][132];   // [k][m], padded stride
  __shared__ float Ws[32][128];   // [k][n]
  int tid = threadIdx.x;
  int row0 = blockIdx.x * 128;
  int col0 = blockIdx.y * 128;
  int tr = (tid >> 4) & 15;
  int tc = tid & 15;

  float acc[8][8];
  #pragma unroll
  for (int i = 0; i < 8; ++i)
    #pragma unroll
    for (int j = 0; j < 8; ++j) acc[i][j] = 0.f;

  for (int k0 = 0; k0 < K; k0 += 32){
    #pragma unroll
    for (int q = 0; q < 4; ++q){
      int idx = tid + q * 256;
      int r  = idx >> 3;
      int kk = (idx & 7) * 4;
      float4 v = make_float4(0.f, 0.f, 0.f, 0.f);
      int gr = row0 + r;
      if (gr < M) v = *reinterpret_cast<const float4*>(A + (size_t)gr * K + k0 + kk);
      As[kk+0][r] = v.x; As[kk+1][r] = v.y; As[kk+2][r] = v.z; As[kk+3][r] = v.w;
    }
    #pragma unroll
    for (int q = 0; q < 4; ++q){
      int idx = tid + q * 256;
      int kk = idx >> 5;
      int cc = (idx & 31) * 4;
      *reinterpret_cast<float4*>(&Ws[kk][cc]) =
          *reinterpret_cast<const float4*>(W + (size_t)(k0 + kk) * Nc + col0 + cc);
    }
    __syncthreads();
    #pragma unroll 8
    for (int kk = 0; kk < 32; ++kk){
      float4 a0 = *reinterpret_cast<const float4*>(&As[kk][tr * 4]);
      float4 a1 = *reinterpret_cast<const float4*>(&As[kk][64 + tr * 4]);
      float4 b0 = *reinterpret_cast<const float4*>(&Ws[kk][tc * 4]);
      float4 b1 = *reinterpret_cast<const float4*>(&Ws[kk][64 + tc * 4]);
      float av[8] = {a0.x, a0.y, a0.z, a0.w, a1.x, a1.y, a1.z, a1.w};
      float bv[8] = {b0.x, b0.y, b0.z, b0.w, b1.x, b1.y, b1.z, b1.w};
      #pragma unroll
      for (int i = 0; i < 8; ++i)
        #pragma unroll
        for (int j = 0; j < 8; ++j)
          acc[i][j] += av[i] * bv[j];
    }
    __syncthreads();
  }

  float4 bia0 = make_float4(0.f, 0.f, 0.f, 0.f), bia1 = bia0;
  if (bias){
    bia0 = *reinterpret_cast<const float4*>(bias + col0 + tc * 4);
    bia1 = *reinterpret_cast<const float4*>(bias + col0 + 64 + tc * 4);
  }
  #pragma unroll
  for (int i = 0; i < 8; ++i){
    int gr = row0 + (i >> 2) * 64 + tr * 4 + (i & 3);
    if (gr < M){
      float4 v0 = make_float4(acc[i][0] + bia0.x, acc[i][1] + bia0.y,
                              acc[i][2] + bia0.z, acc[i][3] + bia0.w);
      float4 v1 = make_float4(acc[i][4] + bia1.x, acc[i][5] + bia1.y,
                              acc[i][6] + bia1.z, acc[i][7] + bia1.w);
      *reinterpret_cast<float4*>(C + (size_t)gr * Nc + col0 + tc * 4) = v0;
      *reinterpret_cast<float4*>(C + (size_t)gr * Nc + col0 + 64 + tc * 4) = v1;
    }
  }
}

// Per edge (128 cols): v = lrelu(F + f_ni[src] + f_nj[dst] + bias);
// ef_out = elu(v) (fused — F is never written back); logits[e][h] = <v_h, attn_h>
__global__ __launch_bounds__(256) void k_edge_build(
    const float* __restrict__ F, const float* __restrict__ f_ni, const float* __restrict__ f_nj,
    const float* __restrict__ bias, const float* __restrict__ attn,
    const int* __restrict__ src, const int* __restrict__ dst,
    float* __restrict__ logits, float* __restrict__ ef_out){
  int tid = threadIdx.x;
  int e = blockIdx.x * 2 + (tid >> 7);
  if (e >= NE) return;
  int c = tid & 127;
  int sN = src[e], dN = dst[e];
  size_t ix = (size_t)e * 128 + c;
  float v = F[ix] + f_ni[sN*128 + c] + f_nj[dN*128 + c] + bias[c];
  v = (v >= 0.f) ? v : 0.01f * v;
  ef_out[ix] = (v > 0.f) ? v : expm1f(v);
  // attn is (4,32) flattened: head h = c>>5 uses attn[h*32 + (c&31)] == attn[c]
  float p = v * attn[c];
  p += __shfl_xor(p, 16, 64);
  p += __shfl_xor(p, 8, 64);
  p += __shfl_xor(p, 4, 64);
  p += __shfl_xor(p, 2, 64);
  p += __shfl_xor(p, 1, 64);
  if ((c & 31) == 0) logits[e * 4 + (c >> 5)] = p;
}

// One block per dst node: fused softmax + weighted aggregation + ELU. No atomics.
// Thread c handles output col c; head h = c>>6.
__global__ __launch_bounds__(256) void k_agg_csr(
    const int* __restrict__ off, const int* __restrict__ perm_e,
    const int* __restrict__ perm_s, const float* __restrict__ logits,
    const float* __restrict__ h_src, float* __restrict__ out){
  int n = blockIdx.x;
  int c = threadIdx.x;
  int h = c >> 6;
  int beg = off[n], end = off[n + 1];
  float m = -INFINITY;
  for (int j = beg; j < end; ++j)
    m = fmaxf(m, logits[perm_e[j] * 4 + h]);
  float acc = 0.f, ssum = 0.f;
  for (int j = beg; j < end; ++j){
    int e = perm_e[j], sN = perm_s[j];
    float ee = expf(logits[e * 4 + h] - m);
    ssum += ee;
    acc += ee * h_src[(size_t)sN * 256 + c];
  }
  float r = (end > beg) ? acc / ssum : 0.f;
  out[(size_t)n * 256 + c] = (r > 0.f) ? r : expm1f(r);
}

static void run_layer(const float* nf, int in_n, const float* ef, int in_e,
                      const float* Wsrc, const float* bsrc, const float* Wni,
                      const float* Wnj, const float* Wfij, const float* attn,
                      const float* bias, const int* src, const int* dst,
                      const int* off, const int* perm_e, const int* perm_s,
                      float* f_ni, float* f_nj, float* h_src, float* F,
                      float* logits, float* nf_out, float* ef_out, hipStream_t stream){
  dim3 gN((NN + 127) / 128, 1);
  dim3 gN2((NN + 127) / 128, 2);
  dim3 gE((NE + 127) / 128, 1);
  k_gemm<<<gN,  256, 0, stream>>>(nf, Wni, nullptr, f_ni, NN, in_n, 128);
  k_gemm<<<gN,  256, 0, stream>>>(nf, Wnj, nullptr, f_nj, NN, in_n, 128);
  k_gemm<<<gN2, 256, 0, stream>>>(nf, Wsrc, bsrc, h_src, NN, in_n, 256);
  k_gemm<<<gE,  256, 0, stream>>>(ef, Wfij, nullptr, F, NE, in_e, 128);
  k_edge_build<<<NE/2, 256, 0, stream>>>(F, f_ni, f_nj, bias, attn, src, dst, logits, ef_out);
  k_agg_csr<<<NN, 256, 0, stream>>>(off, perm_e, perm_s, logits, h_src, nf_out);
}

extern "C" void kernel_launch(void* const* d_in, const int* in_sizes, int n_in,
                              void* d_out, int out_size, void* d_ws, size_t ws_size,
                              hipStream_t stream){
  const int*   node_types = (const int*)d_in[0];
  const int*   src        = (const int*)d_in[1];
  const int*   dst        = (const int*)d_in[2];
  const float* efeats     = (const float*)d_in[3];
  const float* table      = (const float*)d_in[4];
  const float* W_src0 = (const float*)d_in[5];
  const float* b_src0 = (const float*)d_in[6];
  const float* W_ni0  = (const float*)d_in[7];
  const float* W_nj0  = (const float*)d_in[8];
  const float* W_fij0 = (const float*)d_in[9];
  const float* attn0  = (const float*)d_in[10];
  const float* bias0  = (const float*)d_in[11];
  const float* W_src1 = (const float*)d_in[12];
  const float* b_src1 = (const float*)d_in[13];
  const float* W_ni1  = (const float*)d_in[14];
  const float* W_nj1  = (const float*)d_in[15];
  const float* W_fij1 = (const float*)d_in[16];
  const float* attn1  = (const float*)d_in[17];
  const float* bias1  = (const float*)d_in[18];

  char* w = (char*)d_ws;
  auto alloc = [&](size_t bytes){ void* p = (void*)w; w += (bytes + 255) & ~(size_t)255; return p; };
  float* nf_buf = (float*)alloc((size_t)NN * 256 * 4);
  float* f_ni   = (float*)alloc((size_t)NN * 128 * 4);
  float* f_nj   = (float*)alloc((size_t)NN * 128 * 4);
  float* h_src  = (float*)alloc((size_t)NN * 256 * 4);
  float* logits = (float*)alloc((size_t)NE * 4 * 4);
  float* F      = (float*)alloc((size_t)NE * 128 * 4);
  int*   cnt    = (int*)  alloc((size_t)NN * 4);
  int*   cur    = (int*)  alloc((size_t)NN * 4);
  int*   off    = (int*)  alloc((size_t)(NN + 1) * 4);
  int*   perm_e = (int*)  alloc((size_t)NE * 4);
  int*   perm_s = (int*)  alloc((size_t)NE * 4);

  float* out_nf = (float*)d_out;              // (NN, 256)
  float* out_ef = out_nf + (size_t)NN * 256;  // (NE, 128) — also doubles as ef1 staging

  // CSR (dst-grouped edge lists), built once, reused by both layers
  k_zero2<<<(NN + 255)/256, 256, 0, stream>>>(cnt, cur);
  k_hist<<<(NE + 255)/256, 256, 0, stream>>>(dst, cnt);
  k_scan<<<1, 1024, 0, stream>>>(cnt, off);
  k_scatter<<<(NE + 255)/256, 256, 0, stream>>>(src, dst, off, cur, perm_e, perm_s);

  // nf0 = embed_table[node_types]  (NN x 128)
  k_embed<<<(NN*128)/256, 256, 0, stream>>>(node_types, table, nf_buf);

  // Layer 0: in_n=128, in_e=64 -> nf1 (NN x 256) in nf_buf, ef1 (NE x 128) in out_ef
  run_layer(nf_buf, 128, efeats, 64,
            W_src0, b_src0, W_ni0, W_nj0, W_fij0, attn0, bias0,
            src, dst, off, perm_e, perm_s,
            f_ni, f_nj, h_src, F, logits, nf_buf, out_ef, stream);

  // Layer 1: in_n=256, in_e=128 -> outputs straight to d_out
  run_layer(nf_buf, 256, out_ef, 128,
            W_src1, b_src1, W_ni1, W_nj1, W_fij1, attn1, bias1,
            src, dst, off, perm_e, perm_s,
            f_ni, f_nj, h_src, F, logits, out_nf, out_ef, stream);
}

// Round 3
// 1613.817 us; speedup vs baseline: 2.3053x; 1.2991x over previous
//
#include <hip/hip_runtime.h>
#include <hip/hip_bf16.h>

#define NN 50000
#define NE 500000

__global__ void k_embed(const int* __restrict__ nt, const float* __restrict__ table,
                        float* __restrict__ nf){
  int i = blockIdx.x * 256 + threadIdx.x;
  if (i >= NN * 128) return;
  nf[i] = table[nt[i >> 7] * 128 + (i & 127)];
}

// ---------------- CSR build (once per launch; reused by both layers) ----------------
__global__ void k_zero2(int* __restrict__ cnt, int* __restrict__ cur){
  int i = blockIdx.x * 256 + threadIdx.x;
  if (i < NN){ cnt[i] = 0; cur[i] = 0; }
}

__global__ void k_hist(const int* __restrict__ dst, int* __restrict__ cnt){
  int e = blockIdx.x * 256 + threadIdx.x;
  if (e < NE) atomicAdd(&cnt[dst[e]], 1);
}

// single-block exclusive scan over NN counts -> off[0..NN]
__global__ __launch_bounds__(1024) void k_scan(const int* __restrict__ cnt,
                                               int* __restrict__ off){
  __shared__ int ws[16];
  __shared__ int blocktot;
  __shared__ int carry_s;
  int tid = threadIdx.x;
  int lane = tid & 63, wv = tid >> 6;
  if (tid == 0) carry_s = 0;
  for (int base = 0; base < NN; base += 1024){
    int i = base + tid;
    int v = (i < NN) ? cnt[i] : 0;
    int x = v;
    #pragma unroll
    for (int d = 1; d < 64; d <<= 1){
      int t = __shfl_up(x, d, 64);
      if (lane >= d) x += t;
    }
    if (lane == 63) ws[wv] = x;
    __syncthreads();                    // also orders carry_s init
    if (tid == 0){
      int a = 0;
      #pragma unroll
      for (int k2 = 0; k2 < 16; ++k2){ int t = ws[k2]; ws[k2] = a; a += t; }
      blocktot = a;
    }
    __syncthreads();
    int carry = carry_s;
    if (i < NN) off[i] = carry + ws[wv] + (x - v);   // exclusive
    __syncthreads();
    if (tid == 0) carry_s = carry + blocktot;
    __syncthreads();
  }
  if (tid == 0) off[NN] = carry_s;
}

// rank[e] = position of edge e in dst-grouped (CSR) order; perm_s = src in CSR order
__global__ void k_scatter(const int* __restrict__ src, const int* __restrict__ dst,
                          const int* __restrict__ off, int* __restrict__ cur,
                          int* __restrict__ rank, int* __restrict__ perm_s){
  int e = blockIdx.x * 256 + threadIdx.x;
  if (e >= NE) return;
  int d = dst[e];
  int pos = off[d] + atomicAdd(&cur[d], 1);
  rank[e] = pos;
  perm_s[pos] = src[e];
}

// ---------------- GEMM: C[M x Nc] = A[M x K] @ W[K x Nc] (+ bias) ----------------
// Block tile 128x128, 256 threads, 8x8 register micro-tile, BK=32. (node GEMMs)
__global__ __launch_bounds__(256) void k_gemm(
    const float* __restrict__ A, const float* __restrict__ W,
    const float* __restrict__ bias, float* __restrict__ C,
    int M, int K, int Nc){
  __shared__ float As[32][132];   // [k][m], padded stride
  __shared__ float Ws[32][128];   // [k][n]
  int tid = threadIdx.x;
  int row0 = blockIdx.x * 128;
  int col0 = blockIdx.y * 128;
  int tr = (tid >> 4) & 15;
  int tc = tid & 15;

  float acc[8][8];
  #pragma unroll
  for (int i = 0; i < 8; ++i)
    #pragma unroll
    for (int j = 0; j < 8; ++j) acc[i][j] = 0.f;

  for (int k0 = 0; k0 < K; k0 += 32){
    #pragma unroll
    for (int q = 0; q < 4; ++q){
      int idx = tid + q * 256;
      int r  = idx >> 3;
      int kk = (idx & 7) * 4;
      float4 v = make_float4(0.f, 0.f, 0.f, 0.f);
      int gr = row0 + r;
      if (gr < M) v = *reinterpret_cast<const float4*>(A + (size_t)gr * K + k0 + kk);
      As[kk+0][r] = v.x; As[kk+1][r] = v.y; As[kk+2][r] = v.z; As[kk+3][r] = v.w;
    }
    #pragma unroll
    for (int q = 0; q < 4; ++q){
      int idx = tid + q * 256;
      int kk = idx >> 5;
      int cc = (idx & 31) * 4;
      *reinterpret_cast<float4*>(&Ws[kk][cc]) =
          *reinterpret_cast<const float4*>(W + (size_t)(k0 + kk) * Nc + col0 + cc);
    }
    __syncthreads();
    #pragma unroll 8
    for (int kk = 0; kk < 32; ++kk){
      float4 a0 = *reinterpret_cast<const float4*>(&As[kk][tr * 4]);
      float4 a1 = *reinterpret_cast<const float4*>(&As[kk][64 + tr * 4]);
      float4 b0 = *reinterpret_cast<const float4*>(&Ws[kk][tc * 4]);
      float4 b1 = *reinterpret_cast<const float4*>(&Ws[kk][64 + tc * 4]);
      float av[8] = {a0.x, a0.y, a0.z, a0.w, a1.x, a1.y, a1.z, a1.w};
      float bv[8] = {b0.x, b0.y, b0.z, b0.w, b1.x, b1.y, b1.z, b1.w};
      #pragma unroll
      for (int i = 0; i < 8; ++i)
        #pragma unroll
        for (int j = 0; j < 8; ++j)
          acc[i][j] += av[i] * bv[j];
    }
    __syncthreads();
  }

  float4 bia0 = make_float4(0.f, 0.f, 0.f, 0.f), bia1 = bia0;
  if (bias){
    bia0 = *reinterpret_cast<const float4*>(bias + col0 + tc * 4);
    bia1 = *reinterpret_cast<const float4*>(bias + col0 + 64 + tc * 4);
  }
  #pragma unroll
  for (int i = 0; i < 8; ++i){
    int gr = row0 + (i >> 2) * 64 + tr * 4 + (i & 3);
    if (gr < M){
      float4 v0 = make_float4(acc[i][0] + bia0.x, acc[i][1] + bia0.y,
                              acc[i][2] + bia0.z, acc[i][3] + bia0.w);
      float4 v1 = make_float4(acc[i][4] + bia1.x, acc[i][5] + bia1.y,
                              acc[i][6] + bia1.z, acc[i][7] + bia1.w);
      *reinterpret_cast<float4*>(C + (size_t)gr * Nc + col0 + tc * 4) = v0;
      *reinterpret_cast<float4*>(C + (size_t)gr * Nc + col0 + 64 + tc * 4) = v1;
    }
  }
}

// ---------------- Fused edge GEMM + edge_build ----------------
// ef_out = elu(lrelu(A@W + f_ni[src] + f_nj[dst] + bias)); logits (CSR order) from
// in-register head reduction. Nc fixed at 128 (one block covers all cols).
__global__ __launch_bounds__(256) void k_gemm_edge(
    const float* __restrict__ A, const float* __restrict__ W,
    const float* __restrict__ f_ni, const float* __restrict__ f_nj,
    const float* __restrict__ bias, const float* __restrict__ attn,
    const int* __restrict__ src, const int* __restrict__ dst,
    const int* __restrict__ rank,
    float* __restrict__ ef_out, float* __restrict__ logits_csr,
    int M, int K){
  __shared__ float As[32][132];
  __shared__ float Ws[32][128];
  int tid = threadIdx.x;
  int row0 = blockIdx.x * 128;
  int tr = (tid >> 4) & 15;
  int tc = tid & 15;

  float acc[8][8];
  #pragma unroll
  for (int i = 0; i < 8; ++i)
    #pragma unroll
    for (int j = 0; j < 8; ++j) acc[i][j] = 0.f;

  for (int k0 = 0; k0 < K; k0 += 32){
    #pragma unroll
    for (int q = 0; q < 4; ++q){
      int idx = tid + q * 256;
      int r  = idx >> 3;
      int kk = (idx & 7) * 4;
      float4 v = make_float4(0.f, 0.f, 0.f, 0.f);
      int gr = row0 + r;
      if (gr < M) v = *reinterpret_cast<const float4*>(A + (size_t)gr * K + k0 + kk);
      As[kk+0][r] = v.x; As[kk+1][r] = v.y; As[kk+2][r] = v.z; As[kk+3][r] = v.w;
    }
    #pragma unroll
    for (int q = 0; q < 4; ++q){
      int idx = tid + q * 256;
      int kk = idx >> 5;
      int cc = (idx & 31) * 4;
      *reinterpret_cast<float4*>(&Ws[kk][cc]) =
          *reinterpret_cast<const float4*>(W + (size_t)(k0 + kk) * 128 + cc);
    }
    __syncthreads();
    #pragma unroll 8
    for (int kk = 0; kk < 32; ++kk){
      float4 a0 = *reinterpret_cast<const float4*>(&As[kk][tr * 4]);
      float4 a1 = *reinterpret_cast<const float4*>(&As[kk][64 + tr * 4]);
      float4 b0 = *reinterpret_cast<const float4*>(&Ws[kk][tc * 4]);
      float4 b1 = *reinterpret_cast<const float4*>(&Ws[kk][64 + tc * 4]);
      float av[8] = {a0.x, a0.y, a0.z, a0.w, a1.x, a1.y, a1.z, a1.w};
      float bv[8] = {b0.x, b0.y, b0.z, b0.w, b1.x, b1.y, b1.z, b1.w};
      #pragma unroll
      for (int i = 0; i < 8; ++i)
        #pragma unroll
        for (int j = 0; j < 8; ++j)
          acc[i][j] += av[i] * bv[j];
    }
    __syncthreads();
  }

  // Epilogue: cols for this thread are {tc*4+j}j<4 (head tc>>3) and {64+tc*4+j}
  // (head 2+(tc>>3)). attn is (4,32) flattened -> attn[col].
  float4 at0 = *reinterpret_cast<const float4*>(attn + tc * 4);
  float4 at1 = *reinterpret_cast<const float4*>(attn + 64 + tc * 4);
  float4 bi0 = *reinterpret_cast<const float4*>(bias + tc * 4);
  float4 bi1 = *reinterpret_cast<const float4*>(bias + 64 + tc * 4);
  #pragma unroll
  for (int i = 0; i < 8; ++i){
    int gr = row0 + (i >> 2) * 64 + tr * 4 + (i & 3);   // uniform across the 16 tc-lanes
    if (gr >= M) continue;
    int sN = src[gr], dN = dst[gr];
    const float* ni = f_ni + (size_t)sN * 128;
    const float* nj = f_nj + (size_t)dN * 128;
    float4 n0 = *reinterpret_cast<const float4*>(ni + tc * 4);
    float4 n1 = *reinterpret_cast<const float4*>(ni + 64 + tc * 4);
    float4 m0 = *reinterpret_cast<const float4*>(nj + tc * 4);
    float4 m1 = *reinterpret_cast<const float4*>(nj + 64 + tc * 4);
    float v[8];
    v[0] = acc[i][0] + n0.x + m0.x + bi0.x;
    v[1] = acc[i][1] + n0.y + m0.y + bi0.y;
    v[2] = acc[i][2] + n0.z + m0.z + bi0.z;
    v[3] = acc[i][3] + n0.w + m0.w + bi0.w;
    v[4] = acc[i][4] + n1.x + m1.x + bi1.x;
    v[5] = acc[i][5] + n1.y + m1.y + bi1.y;
    v[6] = acc[i][6] + n1.z + m1.z + bi1.z;
    v[7] = acc[i][7] + n1.w + m1.w + bi1.w;
    #pragma unroll
    for (int j = 0; j < 8; ++j) v[j] = (v[j] >= 0.f) ? v[j] : 0.01f * v[j];
    float4 e0 = make_float4(v[0] > 0.f ? v[0] : expm1f(v[0]),
                            v[1] > 0.f ? v[1] : expm1f(v[1]),
                            v[2] > 0.f ? v[2] : expm1f(v[2]),
                            v[3] > 0.f ? v[3] : expm1f(v[3]));
    float4 e1 = make_float4(v[4] > 0.f ? v[4] : expm1f(v[4]),
                            v[5] > 0.f ? v[5] : expm1f(v[5]),
                            v[6] > 0.f ? v[6] : expm1f(v[6]),
                            v[7] > 0.f ? v[7] : expm1f(v[7]));
    *reinterpret_cast<float4*>(ef_out + (size_t)gr * 128 + tc * 4) = e0;
    *reinterpret_cast<float4*>(ef_out + (size_t)gr * 128 + 64 + tc * 4) = e1;
    // logits: p0 covers head (tc>>3), p1 covers head 2+(tc>>3)
    float p0 = v[0]*at0.x + v[1]*at0.y + v[2]*at0.z + v[3]*at0.w;
    float p1 = v[4]*at1.x + v[5]*at1.y + v[6]*at1.z + v[7]*at1.w;
    p0 += __shfl_xor(p0, 1, 64); p0 += __shfl_xor(p0, 2, 64); p0 += __shfl_xor(p0, 4, 64);
    p1 += __shfl_xor(p1, 1, 64); p1 += __shfl_xor(p1, 2, 64); p1 += __shfl_xor(p1, 4, 64);
    float q0 = __shfl_xor(p0, 8, 64);   // other tc-half: head 1 / head 3
    float q1 = __shfl_xor(p1, 8, 64);
    if (tc == 0){
      int pos = rank[gr];
      *reinterpret_cast<float4*>(logits_csr + (size_t)pos * 4) =
          make_float4(p0, q0, p1, q1);  // heads 0,1,2,3
    }
  }
}

// One block per dst node: fused softmax + weighted aggregation + ELU. No atomics.
// logits are already in CSR order -> streaming reads.
__global__ __launch_bounds__(256) void k_agg_csr(
    const int* __restrict__ off, const int* __restrict__ perm_s,
    const float* __restrict__ logits_csr, const float* __restrict__ h_src,
    float* __restrict__ out){
  int n = blockIdx.x;
  int c = threadIdx.x;
  int h = c >> 6;
  int beg = off[n], end = off[n + 1];
  float m = -INFINITY;
  for (int j = beg; j < end; ++j)
    m = fmaxf(m, logits_csr[(size_t)j * 4 + h]);
  float acc = 0.f, ssum = 0.f;
  for (int j = beg; j < end; ++j){
    float ee = expf(logits_csr[(size_t)j * 4 + h] - m);
    ssum += ee;
    acc += ee * h_src[(size_t)perm_s[j] * 256 + c];
  }
  float r = (end > beg) ? acc / ssum : 0.f;
  out[(size_t)n * 256 + c] = (r > 0.f) ? r : expm1f(r);
}

static void run_layer(const float* nf, int in_n, const float* ef, int in_e,
                      const float* Wsrc, const float* bsrc, const float* Wni,
                      const float* Wnj, const float* Wfij, const float* attn,
                      const float* bias, const int* src, const int* dst,
                      const int* off, const int* rank, const int* perm_s,
                      float* f_ni, float* f_nj, float* h_src, float* logits,
                      float* nf_out, float* ef_out, hipStream_t stream){
  dim3 gN((NN + 127) / 128, 1);
  dim3 gN2((NN + 127) / 128, 2);
  k_gemm<<<gN,  256, 0, stream>>>(nf, Wni, nullptr, f_ni, NN, in_n, 128);
  k_gemm<<<gN,  256, 0, stream>>>(nf, Wnj, nullptr, f_nj, NN, in_n, 128);
  k_gemm<<<gN2, 256, 0, stream>>>(nf, Wsrc, bsrc, h_src, NN, in_n, 256);
  k_gemm_edge<<<(NE + 127) / 128, 256, 0, stream>>>(
      ef, Wfij, f_ni, f_nj, bias, attn, src, dst, rank, ef_out, logits, NE, in_e);
  k_agg_csr<<<NN, 256, 0, stream>>>(off, perm_s, logits, h_src, nf_out);
}

extern "C" void kernel_launch(void* const* d_in, const int* in_sizes, int n_in,
                              void* d_out, int out_size, void* d_ws, size_t ws_size,
                              hipStream_t stream){
  const int*   node_types = (const int*)d_in[0];
  const int*   src        = (const int*)d_in[1];
  const int*   dst        = (const int*)d_in[2];
  const float* efeats     = (const float*)d_in[3];
  const float* table      = (const float*)d_in[4];
  const float* W_src0 = (const float*)d_in[5];
  const float* b_src0 = (const float*)d_in[6];
  const float* W_ni0  = (const float*)d_in[7];
  const float* W_nj0  = (const float*)d_in[8];
  const float* W_fij0 = (const float*)d_in[9];
  const float* attn0  = (const float*)d_in[10];
  const float* bias0  = (const float*)d_in[11];
  const float* W_src1 = (const float*)d_in[12];
  const float* b_src1 = (const float*)d_in[13];
  const float* W_ni1  = (const float*)d_in[14];
  const float* W_nj1  = (const float*)d_in[15];
  const float* W_fij1 = (const float*)d_in[16];
  const float* attn1  = (const float*)d_in[17];
  const float* bias1  = (const float*)d_in[18];

  char* w = (char*)d_ws;
  auto alloc = [&](size_t bytes){ void* p = (void*)w; w += (bytes + 255) & ~(size_t)255; return p; };
  float* nf_buf = (float*)alloc((size_t)NN * 256 * 4);
  float* f_ni   = (float*)alloc((size_t)NN * 128 * 4);
  float* f_nj   = (float*)alloc((size_t)NN * 128 * 4);
  float* h_src  = (float*)alloc((size_t)NN * 256 * 4);
  float* logits = (float*)alloc((size_t)NE * 4 * 4);
  int*   cnt    = (int*)  alloc((size_t)NN * 4);
  int*   cur    = (int*)  alloc((size_t)NN * 4);
  int*   off    = (int*)  alloc((size_t)(NN + 1) * 4);
  int*   rank   = (int*)  alloc((size_t)NE * 4);
  int*   perm_s = (int*)  alloc((size_t)NE * 4);

  float* out_nf = (float*)d_out;              // (NN, 256)
  float* out_ef = out_nf + (size_t)NN * 256;  // (NE, 128) — also doubles as ef1 staging

  // CSR (dst-grouped edge lists), built once, reused by both layers
  k_zero2<<<(NN + 255)/256, 256, 0, stream>>>(cnt, cur);
  k_hist<<<(NE + 255)/256, 256, 0, stream>>>(dst, cnt);
  k_scan<<<1, 1024, 0, stream>>>(cnt, off);
  k_scatter<<<(NE + 255)/256, 256, 0, stream>>>(src, dst, off, cur, rank, perm_s);

  // nf0 = embed_table[node_types]  (NN x 128)
  k_embed<<<(NN*128)/256, 256, 0, stream>>>(node_types, table, nf_buf);

  // Layer 0: in_n=128, in_e=64 -> nf1 (NN x 256) in nf_buf, ef1 (NE x 128) in out_ef
  run_layer(nf_buf, 128, efeats, 64,
            W_src0, b_src0, W_ni0, W_nj0, W_fij0, attn0, bias0,
            src, dst, off, rank, perm_s,
            f_ni, f_nj, h_src, logits, nf_buf, out_ef, stream);

  // Layer 1: in_n=256, in_e=128 -> outputs straight to d_out
  run_layer(nf_buf, 256, out_ef, 128,
            W_src1, b_src1, W_ni1, W_nj1, W_fij1, attn1, bias1,
            src, dst, off, rank, perm_s,
            f_ni, f_nj, h_src, logits, out_nf, out_ef, stream);
}